// Round 1
// baseline (364.641 us; speedup 1.0000x reference)
//
#include <hip/hip_runtime.h>

// KVCacheManager: out[0] = transpose(K[:, :, :, :S]) (B,H,D,S)->(B,H,S,D)
//                 out[1] = V[:, :, :S, :] contiguous copy
// Pure data movement, fp32. Roofline ~402 MB @ ~6.3 TB/s ~= 64 us.
//
// K transpose without LDS: lane -> d mapping. Each lane streams one K row
// (contiguous float4 loads along s); a wave's 64 lanes then hold 64
// consecutive d values for each s, so stores are 256 B contiguous per
// instruction. V part: straight float4 chunk copy.

#define BH 32          // B*H = 4*8
#define DD 128         // head dim

__global__ __launch_bounds__(256) void kv_repack(
    const float* __restrict__ kc, const float* __restrict__ vc,
    float* __restrict__ out,
    int S, int Sfull, int kBlocks, int vBlocksPerBH, int f4PerVBlock)
{
    const int bid = blockIdx.x;
    if (bid < kBlocks) {
        // ---- K transpose: one block = one (b,h) x 128 s-values ----
        const int sTilesPerBH = S >> 7;              // S/128
        const int bh    = bid / sTilesPerBH;
        const int sTile = bid - bh * sTilesPerBH;
        const int t     = threadIdx.x;
        const int lane  = t & 63;
        const int wave  = t >> 6;                    // 4 waves
        const int dhalf = wave & 1;                  // d in [0,64) or [64,128)
        const int ssub  = wave >> 1;                 // which 64-s subtile
        const int d     = (dhalf << 6) + lane;
        const int s0    = (sTile << 7) + (ssub << 6);

        const float* src = kc + (size_t)(bh * DD + d) * (size_t)Sfull + s0;
        float* dst = out + ((size_t)bh * S + s0) * DD + (dhalf << 6) + lane;

#pragma unroll
        for (int j = 0; j < 16; ++j) {               // 64 s-values, float4 at a time
            float4 v4 = *(const float4*)(src + (j << 2));
            float* drow = dst + (size_t)(j << 2) * DD;
            drow[0]       = v4.x;   // row s0+4j+0, col d  (wave: 256B contiguous)
            drow[DD]      = v4.y;
            drow[2 * DD]  = v4.z;
            drow[3 * DD]  = v4.w;
        }
    } else {
        // ---- V copy: contiguous float4 chunk copy per (b,h) ----
        const int vb   = bid - kBlocks;
        const int bh   = vb / vBlocksPerBH;
        const int part = vb - bh * vBlocksPerBH;

        const size_t f4PerBHsrc = (size_t)Sfull * (DD / 4);   // Sfull*32
        const size_t f4PerBHdst = (size_t)S * (DD / 4);       // S*32
        const size_t outVOff    = (size_t)BH * S * (DD / 4);  // K part size in float4

        const float4* src = (const float4*)vc + (size_t)bh * f4PerBHsrc
                            + (size_t)part * f4PerVBlock;
        float4* dst = (float4*)out + outVOff + (size_t)bh * f4PerBHdst
                      + (size_t)part * f4PerVBlock;

        for (int i = threadIdx.x; i < f4PerVBlock; i += 256)
            dst[i] = src[i];
    }
}

extern "C" void kernel_launch(void* const* d_in, const int* in_sizes, int n_in,
                              void* d_out, int out_size, void* d_ws, size_t ws_size,
                              hipStream_t stream) {
    const float* kc = (const float*)d_in[0];
    const float* vc = (const float*)d_in[1];
    float* out = (float*)d_out;

    // Derive shapes host-side (no device reads): out = (2, B,H, S, D)
    const int S     = out_size / (2 * BH * DD);          // 6144
    const int Sfull = in_sizes[0] / (BH * DD);           // 8192

    const int kBlocks       = BH * (S >> 7);             // 32*48 = 1536
    const int vBlocksPerBH  = S >> 7;                    // 48
    const int f4PerVBlock   = (S * (DD / 4)) / vBlocksPerBH; // 4096
    const int vBlocks       = BH * vBlocksPerBH;         // 1536

    dim3 grid(kBlocks + vBlocks);
    dim3 block(256);
    kv_repack<<<grid, block, 0, stream>>>(kc, vc, out, S, Sfull,
                                          kBlocks, vBlocksPerBH, f4PerVBlock);
}

// Round 2
// 357.299 us; speedup vs baseline: 1.0205x; 1.0205x over previous
//
#include <hip/hip_runtime.h>

// KVCacheManager: out[0] = transpose(K[:, :, :, :S]) (B,H,D,S)->(B,H,S,D)
//                 out[1] = V[:, :, :S, :] contiguous copy
// Pure data movement, fp32. Roofline ~402 MB @ ~6.3 TB/s ~= 64 us.
//
// Round 1 (364 us): lane->d direct transpose made every K load touch 64
// cache lines 32KB apart (8x over-fetch + transaction serialization).
// Round 2: LDS-staged transpose. Tile 64(d) x 128(s) per block.
//   stage 1: coalesced float4 reads along s (wave = 2x512B segments),
//            scalar LDS writes into [64][129] padded layout (4-way, 1.58x)
//   stage 2: LDS reads along d (2-way = free), coalesced float4 stores
//            along d (wave = 4x256B segments).
// V part: straight float4 chunk copy (already streaming).

#define BH 32          // B*H = 4*8
#define DD 128         // head dim
#define LDS_STRIDE 129 // 128 + 1 pad

__global__ __launch_bounds__(256) void kv_repack(
    const float* __restrict__ kc, const float* __restrict__ vc,
    float* __restrict__ out,
    int S, int Sfull, int kBlocks, int vBlocksPerBH, int f4PerVBlock)
{
    __shared__ float lds[64 * LDS_STRIDE];   // 33,024 B

    const int bid = blockIdx.x;
    const int t = threadIdx.x;

    if (bid < kBlocks) {
        // ---- K transpose: one block = 64(d) x 128(s) tile ----
        const int sTiles = S >> 7;              // S/128 = 48
        const int perBH  = 2 * sTiles;          // 2 d-tiles
        const int bh     = bid / perBH;
        const int rem    = bid - bh * perBH;
        const int dTile  = rem / sTiles;        // 0 or 1 (64-wide d halves)
        const int sTile  = rem - dTile * sTiles;

        // stage 1: global -> LDS. idx = i*256 + t; d = idx/32, s4 = idx%32.
        // Wave: lanes 0-31 same d-row, s contiguous -> 2x512B per load instr.
        {
            const int s4 = t & 31;              // float4 column in s
            const int d0 = t >> 5;              // 0..7
            const float* src = kc
                + (size_t)(bh * DD + dTile * 64) * (size_t)Sfull
                + (size_t)(sTile << 7) + (s4 << 2);
#pragma unroll
            for (int i = 0; i < 8; ++i) {
                const int d = d0 + (i << 3);    // 0..63
                float4 v = *(const float4*)(src + (size_t)d * Sfull);
                float* L = &lds[d * LDS_STRIDE + (s4 << 2)];
                L[0] = v.x; L[1] = v.y; L[2] = v.z; L[3] = v.w;
            }
        }
        __syncthreads();

        // stage 2: LDS -> global. Wave: lanes 0-15 one dest row (256B), 4 rows
        // per store instr. LDS read banks: 2-way (free).
        {
            const int d4 = t & 15;              // float4 column in d (64-wide)
            const int r0 = t >> 4;              // 0..15
            float* dstBase = out
                + ((size_t)bh * S + (size_t)(sTile << 7)) * DD
                + dTile * 64 + (d4 << 2);
#pragma unroll
            for (int i = 0; i < 8; ++i) {
                const int sr = (i << 4) + r0;   // 0..127
                float4 v;
                v.x = lds[(4 * d4 + 0) * LDS_STRIDE + sr];
                v.y = lds[(4 * d4 + 1) * LDS_STRIDE + sr];
                v.z = lds[(4 * d4 + 2) * LDS_STRIDE + sr];
                v.w = lds[(4 * d4 + 3) * LDS_STRIDE + sr];
                *(float4*)(dstBase + (size_t)sr * DD) = v;
            }
        }
    } else {
        // ---- V copy: contiguous float4 chunk copy per (b,h) ----
        const int vb   = bid - kBlocks;
        const int bh   = vb / vBlocksPerBH;
        const int part = vb - bh * vBlocksPerBH;

        const size_t f4PerBHsrc = (size_t)Sfull * (DD / 4);
        const size_t f4PerBHdst = (size_t)S * (DD / 4);
        const size_t outVOff    = (size_t)BH * S * (DD / 4);

        const float4* src = (const float4*)vc + (size_t)bh * f4PerBHsrc
                            + (size_t)part * f4PerVBlock;
        float4* dst = (float4*)out + outVOff + (size_t)bh * f4PerBHdst
                      + (size_t)part * f4PerVBlock;

        for (int i = t; i < f4PerVBlock; i += 256)
            dst[i] = src[i];
    }
}

extern "C" void kernel_launch(void* const* d_in, const int* in_sizes, int n_in,
                              void* d_out, int out_size, void* d_ws, size_t ws_size,
                              hipStream_t stream) {
    const float* kc = (const float*)d_in[0];
    const float* vc = (const float*)d_in[1];
    float* out = (float*)d_out;

    // Derive shapes host-side: out = (2, B,H, S, D)
    const int S     = out_size / (2 * BH * DD);          // 6144
    const int Sfull = in_sizes[0] / (BH * DD);           // 8192

    const int sTiles        = S >> 7;                    // 48
    const int kBlocks       = BH * 2 * sTiles;           // 3072
    const int vBlocksPerBH  = sTiles;                    // 48
    const int f4PerVBlock   = (S * (DD / 4)) / vBlocksPerBH; // 4096
    const int vBlocks       = BH * vBlocksPerBH;         // 1536

    dim3 grid(kBlocks + vBlocks);
    dim3 block(256);
    kv_repack<<<grid, block, 0, stream>>>(kc, vc, out, S, Sfull,
                                          kBlocks, vBlocksPerBH, f4PerVBlock);
}